// Round 1
// baseline (145.007 us; speedup 1.0000x reference)
//
#include <hip/hip_runtime.h>
#include <hip/hip_bf16.h>

typedef unsigned short u16;
typedef __attribute__((ext_vector_type(8))) short bf16x8;   // 8 bf16 = 4 VGPRs (MFMA A/B frag)
typedef __attribute__((ext_vector_type(4))) float f32x4;    // MFMA C/D frag

#define BB 4
#define NN 2048
#define DD 256
#define HH 8
#define BN (BB*NN)   // 8192 rows

__device__ inline u16 bfu(float f) {
  __hip_bfloat16 h = __float2bfloat16(f);
  return *reinterpret_cast<u16*>(&h);
}

// ---------------- prep: x = qdt + boxes (fp32 + bf16) ----------------
__global__ __launch_bounds__(256) void prep_x_kernel(const float* __restrict__ qdt,
    const float* __restrict__ boxes, float* __restrict__ x, u16* __restrict__ xb) {
  int i = blockIdx.x * 256 + threadIdx.x;           // 524288 float4 groups
  float4 a = ((const float4*)qdt)[i];
  float4 b = ((const float4*)boxes)[i];
  float4 v = make_float4(a.x + b.x, a.y + b.y, a.z + b.z, a.w + b.w);
  ((float4*)x)[i] = v;
  ((ushort4*)xb)[i] = make_ushort4(bfu(v.x), bfu(v.y), bfu(v.z), bfu(v.w));
}

// ---------------- prep: mask int32 -> u8 ----------------
__global__ __launch_bounds__(256) void prep_mask_kernel(const int* __restrict__ mask,
    unsigned char* __restrict__ m8) {
  int i = blockIdx.x * 256 + threadIdx.x;           // 1048576 int4 groups
  int4 m = ((const int4*)mask)[i];
  ((uchar4*)m8)[i] = make_uchar4((unsigned char)m.x, (unsigned char)m.y,
                                 (unsigned char)m.z, (unsigned char)m.w);
}

// ---------------- prep: transpose weights to bf16 W^T, concat qkv bias ----------------
__global__ __launch_bounds__(256) void prep_w_kernel(
    const float* __restrict__ Wq, const float* __restrict__ Wk, const float* __restrict__ Wv,
    const float* __restrict__ Wo, const float* __restrict__ W1, const float* __restrict__ W2,
    const float* __restrict__ bq, const float* __restrict__ bk, const float* __restrict__ bv,
    u16* __restrict__ wqkvT, u16* __restrict__ woT, u16* __restrict__ w1T, u16* __restrict__ w2T,
    float* __restrict__ bqkv) {
  int i = blockIdx.x * 256 + threadIdx.x;
  if (i < 196608) {                    // wqkvT[n][k] = W*[k][n],  n in [0,768)
    int n = i >> 8, k = i & 255;
    const float* src = (n < 256) ? Wq : (n < 512 ? Wk : Wv);
    wqkvT[i] = bfu(src[k * 256 + (n & 255)]);
  } else if (i < 262144) {
    int j = i - 196608; int n = j >> 8, k = j & 255;
    woT[j] = bfu(Wo[k * 256 + n]);
  } else if (i < 327680) {
    int j = i - 262144; int n = j >> 8, k = j & 255;
    w1T[j] = bfu(W1[k * 256 + n]);
  } else if (i < 393216) {
    int j = i - 327680; int n = j >> 8, k = j & 255;
    w2T[j] = bfu(W2[k * 256 + n]);
  } else if (i < 393984) {
    int n = i - 393216;
    bqkv[n] = (n < 256) ? bq[n] : (n < 512 ? bk[n - 256] : bv[n - 512]);
  }
}

// ---------------- GEMM: C[M,Ncols] = A[M,256](bf16) @ W (via W^T bf16) + bias ----------------
// 64x64 tile, 4 waves, each wave 16 rows x 64 cols. K=256 staged fully in LDS.
// MODE 0: bf16 store (qkv). MODE 1: relu + bf16 store. MODE 2: fp32 store of acc+bias+res.
template<int MODE>
__global__ __launch_bounds__(256) void gemm256_kernel(
    const u16* __restrict__ A, const u16* __restrict__ Bt,
    const float* __restrict__ bias, const float* res,
    void* out, int ldout) {
  __shared__ u16 At[64][264];   // +8 pad: row stride 132 dw -> 2-way (free) bank aliasing
  __shared__ u16 Bs[64][264];
  const int m0 = blockIdx.x * 64;
  const int n0 = blockIdx.y * 64;
  const int t = threadIdx.x;
  {
    const int row = t >> 2, cb = (t & 3) * 64;
    const u16* ga = A  + (size_t)(m0 + row) * 256 + cb;
    const u16* gb = Bt + (size_t)(n0 + row) * 256 + cb;
#pragma unroll
    for (int i = 0; i < 8; ++i) {
      *(int4*)&At[row][cb + i * 8] = *(const int4*)(ga + i * 8);
      *(int4*)&Bs[row][cb + i * 8] = *(const int4*)(gb + i * 8);
    }
  }
  __syncthreads();
  const int w = t >> 6, l = t & 63, g = l >> 4, c = l & 15;
  f32x4 acc[4] = {};
#pragma unroll
  for (int kk = 0; kk < 256; kk += 32) {
    bf16x8 af = *(const bf16x8*)&At[w * 16 + c][kk + g * 8];
#pragma unroll
    for (int j = 0; j < 4; ++j) {
      bf16x8 bfr = *(const bf16x8*)&Bs[j * 16 + c][kk + g * 8];
      acc[j] = __builtin_amdgcn_mfma_f32_16x16x32_bf16(af, bfr, acc[j], 0, 0, 0);
    }
  }
#pragma unroll
  for (int j = 0; j < 4; ++j) {
#pragma unroll
    for (int r = 0; r < 4; ++r) {
      int m = m0 + w * 16 + g * 4 + r;       // C/D: row = 4*(lane>>4)+reg, col = lane&15
      int n = n0 + j * 16 + c;
      float v = acc[j][r] + bias[n];
      size_t oi = (size_t)m * ldout + n;
      if (MODE == 0) {
        ((u16*)out)[oi] = bfu(v);
      } else if (MODE == 1) {
        ((u16*)out)[oi] = bfu(v > 0.f ? v : 0.f);
      } else {
        ((float*)out)[oi] = v + res[(size_t)m * 256 + n];
      }
    }
  }
}

// ---------------- fused sigmoid-gated attention ----------------
// block = (b, h, 64 q-rows); 4 waves x 16 q-rows. Loop k in tiles of 64.
__global__ __launch_bounds__(256) void attn_kernel(
    const u16* __restrict__ qkv,            // [B*N, 768] bf16 (q|k|v)
    const unsigned char* __restrict__ m8,   // [N,N] 0/1
    u16* __restrict__ ob) {                 // [B*N, 256] bf16
  __shared__ u16 Klds[64][40];              // K rows, +8 pad
  __shared__ u16 Vt[32][72];                // V transposed [dh][k], +8 pad
  __shared__ u16 Plds[4][16][72];           // per-wave P re-layout buffer
  const int bid = blockIdx.x;
  const int qt = bid & 31, h = (bid >> 5) & 7, b = bid >> 8;
  const int q0 = qt * 64;
  const int t = threadIdx.x, w = t >> 6, l = t & 63, g = l >> 4, c = l & 15;
  const size_t base = (size_t)b * NN * 768;

  // Q fragment (held in regs): A-frag row = lane&15, k = 8*(lane>>4)+j
  bf16x8 qf = *(const bf16x8*)(qkv + base + (size_t)(q0 + w * 16 + c) * 768 + h * 32 + g * 8);
  f32x4 oacc[2] = {};

  const int krow = t >> 2, dh = (t & 3) * 8;
  const u16* kbase = qkv + base + 256 + h * 32;
  const u16* vbase = qkv + base + 512 + h * 32;
  const f32x4 zero = {0.f, 0.f, 0.f, 0.f};

  for (int kt = 0; kt < NN; kt += 64) {
    // cooperative stage: K rows, V transposed
    *(int4*)&Klds[krow][dh] = *(const int4*)(kbase + (size_t)(kt + krow) * 768 + dh);
    {
      bf16x8 vv = *(const bf16x8*)(vbase + (size_t)(kt + krow) * 768 + dh);
#pragma unroll
      for (int j = 0; j < 8; ++j) Vt[dh + j][krow] = ((u16*)&vv)[j];
    }
    __syncthreads();

    // S = Q K^T (4 x 16x16 tiles), sigmoid*mask, write P to wave-private LDS
#pragma unroll
    for (int k16 = 0; k16 < 4; ++k16) {
      bf16x8 kf = *(const bf16x8*)&Klds[k16 * 16 + c][g * 8];
      f32x4 s = __builtin_amdgcn_mfma_f32_16x16x32_bf16(qf, kf, zero, 0, 0, 0);
      const int kg = kt + k16 * 16 + c;
#pragma unroll
      for (int r = 0; r < 4; ++r) {
        const int qrow = q0 + w * 16 + g * 4 + r;
        float sv = s[r] * 0.1767766953f;                 // 1/sqrt(32)
        float mv = (float)m8[(size_t)qrow * NN + kg];
        float p = mv * __builtin_amdgcn_rcpf(1.f + __expf(-sv));
        Plds[w][g * 4 + r][k16 * 16 + c] = bfu(p);
      }
    }
    // PV: O += P @ V  (P re-read in A-frag layout, V from transposed LDS)
#pragma unroll
    for (int kk = 0; kk < 2; ++kk) {
      bf16x8 pf = *(const bf16x8*)&Plds[w][c][kk * 32 + g * 8];
#pragma unroll
      for (int d0 = 0; d0 < 2; ++d0) {
        bf16x8 vf = *(const bf16x8*)&Vt[d0 * 16 + c][kk * 32 + g * 8];
        oacc[d0] = __builtin_amdgcn_mfma_f32_16x16x32_bf16(pf, vf, oacc[d0], 0, 0, 0);
      }
    }
    __syncthreads();
  }
#pragma unroll
  for (int d0 = 0; d0 < 2; ++d0)
#pragma unroll
    for (int r = 0; r < 4; ++r) {
      const int qrow = q0 + w * 16 + g * 4 + r;
      ob[(size_t)(b * NN + qrow) * 256 + h * 32 + d0 * 16 + c] = bfu(oacc[d0][r]);
    }
}

// ---------------- LayerNorm: wave per row ----------------
template<int WB>
__global__ __launch_bounds__(256) void ln_kernel(const float* y,
    const float* __restrict__ gam, const float* __restrict__ bet,
    float* outf, u16* outb) {
  const int row = blockIdx.x * 4 + (threadIdx.x >> 6);
  const int l = threadIdx.x & 63;
  const float4 v = ((const float4*)(y + (size_t)row * DD))[l];
  float s1 = v.x + v.y + v.z + v.w;
  float s2 = v.x * v.x + v.y * v.y + v.z * v.z + v.w * v.w;
#pragma unroll
  for (int off = 1; off < 64; off <<= 1) {
    s1 += __shfl_xor(s1, off);
    s2 += __shfl_xor(s2, off);
  }
  const float mean = s1 * (1.f / DD);
  const float var = s2 * (1.f / DD) - mean * mean;
  const float inv = rsqrtf(var + 1e-5f);
  const float4 gg = ((const float4*)gam)[l];
  const float4 bb = ((const float4*)bet)[l];
  float o0 = (v.x - mean) * inv * gg.x + bb.x;
  float o1 = (v.y - mean) * inv * gg.y + bb.y;
  float o2 = (v.z - mean) * inv * gg.z + bb.z;
  float o3 = (v.w - mean) * inv * gg.w + bb.w;
  ((float4*)(outf + (size_t)row * DD))[l] = make_float4(o0, o1, o2, o3);
  if (WB) {
    ((ushort4*)(outb + (size_t)row * DD))[l] = make_ushort4(bfu(o0), bfu(o1), bfu(o2), bfu(o3));
  }
}

extern "C" void kernel_launch(void* const* d_in, const int* in_sizes, int n_in,
                              void* d_out, int out_size, void* d_ws, size_t ws_size,
                              hipStream_t stream) {
  const float* qdt   = (const float*)d_in[0];
  const float* boxes = (const float*)d_in[1];
  const int*   mask  = (const int*)d_in[2];
  const float* Wq = (const float*)d_in[3];
  const float* bq = (const float*)d_in[4];
  const float* Wk = (const float*)d_in[5];
  const float* bk = (const float*)d_in[6];
  const float* Wv = (const float*)d_in[7];
  const float* bv = (const float*)d_in[8];
  const float* Wo = (const float*)d_in[9];
  const float* bo = (const float*)d_in[10];
  const float* W1 = (const float*)d_in[11];
  const float* b1 = (const float*)d_in[12];
  const float* W2 = (const float*)d_in[13];
  const float* b2 = (const float*)d_in[14];
  const float* g1  = (const float*)d_in[15];
  const float* be1 = (const float*)d_in[16];
  const float* g2  = (const float*)d_in[17];
  const float* be2 = (const float*)d_in[18];

  char* ws = (char*)d_ws;
  float* x    = (float*)(ws + 0);          // [8192,256] f32; later reused as y2
  u16*   xb   = (u16*)  (ws + 8388608);    // [8192,256] bf16
  u16*   qkv  = (u16*)  (ws + 12582912);   // [8192,768] bf16
  u16*   obuf = (u16*)  (ws + 25165824);   // [8192,256] bf16 attention out
  float* y1   = (float*)(ws + 29360128);   // [8192,256] f32 (x+attn_out -> LN1 in-place -> t1)
  u16*   t1b  = (u16*)  (ws + 37748736);   // [8192,256] bf16
  u16*   f1b  = (u16*)  (ws + 41943040);   // [8192,256] bf16 relu(ff1)
  u16*   wqkvT= (u16*)  (ws + 46137344);   // [768,256] bf16
  u16*   woT  = (u16*)  (ws + 46530560);
  u16*   w1T  = (u16*)  (ws + 46661632);
  u16*   w2T  = (u16*)  (ws + 46792704);
  float* bqkv = (float*)(ws + 46923776);   // [768] f32
  unsigned char* m8 = (unsigned char*)(ws + 46926848);  // [2048,2048] u8

  prep_x_kernel<<<2048, 256, 0, stream>>>(qdt, boxes, x, xb);
  prep_mask_kernel<<<4096, 256, 0, stream>>>(mask, m8);
  prep_w_kernel<<<1539, 256, 0, stream>>>(Wq, Wk, Wv, Wo, W1, W2, bq, bk, bv,
                                          wqkvT, woT, w1T, w2T, bqkv);
  // fused QKV projection: [8192,256] x [256,768]
  gemm256_kernel<0><<<dim3(128, 12), 256, 0, stream>>>(xb, wqkvT, bqkv, nullptr, qkv, 768);
  // attention
  attn_kernel<<<1024, 256, 0, stream>>>(qkv, m8, obuf);
  // attn_out = O@Wo + bo + x  (fp32)
  gemm256_kernel<2><<<dim3(128, 4), 256, 0, stream>>>(obuf, woT, bo, x, y1, 256);
  // LN1 in-place + bf16 copy
  ln_kernel<1><<<2048, 256, 0, stream>>>(y1, g1, be1, y1, t1b);
  // FF1 + relu
  gemm256_kernel<1><<<dim3(128, 4), 256, 0, stream>>>(t1b, w1T, b1, nullptr, f1b, 256);
  // FF2 + b2 + t1  (fp32) -> reuse x buffer
  gemm256_kernel<2><<<dim3(128, 4), 256, 0, stream>>>(f1b, w2T, b2, y1, x, 256);
  // LN2 -> d_out
  ln_kernel<0><<<2048, 256, 0, stream>>>(x, g2, be2, (float*)d_out, nullptr);
}

// Round 2
// 142.359 us; speedup vs baseline: 1.0186x; 1.0186x over previous
//
#include <hip/hip_runtime.h>
#include <hip/hip_bf16.h>

typedef unsigned short u16;
typedef unsigned int u32;
typedef __attribute__((ext_vector_type(8))) short bf16x8;   // 8 bf16 = 4 VGPRs (MFMA A/B frag)
typedef __attribute__((ext_vector_type(4))) float f32x4;    // MFMA C/D frag

#define BB 4
#define NN 2048
#define DD 256
#define HH 8
#define LAMBDA 0.2550351f   // log2(e)/sqrt(32): folded into Q so sigmoid uses native exp2
#define BIGM 1024.0f

__device__ inline u16 bfu(float f) {
  __hip_bfloat16 h = __float2bfloat16(f);
  return *reinterpret_cast<u16*>(&h);
}

// ---------------- prep: x = qdt + boxes (fp32 + bf16) ----------------
__global__ __launch_bounds__(256) void prep_x_kernel(const float* __restrict__ qdt,
    const float* __restrict__ boxes, float* __restrict__ x, u16* __restrict__ xb) {
  int i = blockIdx.x * 256 + threadIdx.x;
  float4 a = ((const float4*)qdt)[i];
  float4 b = ((const float4*)boxes)[i];
  float4 v = make_float4(a.x + b.x, a.y + b.y, a.z + b.z, a.w + b.w);
  ((float4*)x)[i] = v;
  ((ushort4*)xb)[i] = make_ushort4(bfu(v.x), bfu(v.y), bfu(v.z), bfu(v.w));
}

// ---------------- prep: mask int32 -> u8 ----------------
__global__ __launch_bounds__(256) void prep_mask_kernel(const int* __restrict__ mask,
    unsigned char* __restrict__ m8) {
  int i = blockIdx.x * 256 + threadIdx.x;
  int4 m = ((const int4*)mask)[i];
  ((uchar4*)m8)[i] = make_uchar4((unsigned char)m.x, (unsigned char)m.y,
                                 (unsigned char)m.z, (unsigned char)m.w);
}

// ---------------- prep: transpose weights to bf16 W^T, concat qkv bias ----------------
__global__ __launch_bounds__(256) void prep_w_kernel(
    const float* __restrict__ Wq, const float* __restrict__ Wk, const float* __restrict__ Wv,
    const float* __restrict__ Wo, const float* __restrict__ W1, const float* __restrict__ W2,
    const float* __restrict__ bq, const float* __restrict__ bk, const float* __restrict__ bv,
    u16* __restrict__ wqkvT, u16* __restrict__ woT, u16* __restrict__ w1T, u16* __restrict__ w2T,
    float* __restrict__ bqkv) {
  int i = blockIdx.x * 256 + threadIdx.x;
  if (i < 196608) {                    // wqkvT[n][k] = W*[k][n],  n in [0,768)
    int n = i >> 8, k = i & 255;
    const float* src = (n < 256) ? Wq : (n < 512 ? Wk : Wv);
    wqkvT[i] = bfu(src[k * 256 + (n & 255)]);
  } else if (i < 262144) {
    int j = i - 196608; int n = j >> 8, k = j & 255;
    woT[j] = bfu(Wo[k * 256 + n]);
  } else if (i < 327680) {
    int j = i - 262144; int n = j >> 8, k = j & 255;
    w1T[j] = bfu(W1[k * 256 + n]);
  } else if (i < 393216) {
    int j = i - 327680; int n = j >> 8, k = j & 255;
    w2T[j] = bfu(W2[k * 256 + n]);
  } else if (i < 393984) {
    int n = i - 393216;
    bqkv[n] = (n < 256) ? bq[n] : (n < 512 ? bk[n - 256] : bv[n - 512]);
  }
}

// ============ shared GEMM body: C = A[M,256] @ Bt[N,256]^T, 64x64 tile ============
#define GEMM_BODY()                                                              \
  __shared__ u16 At[64][264];                                                    \
  __shared__ u16 Bs[64][264];                                                    \
  const int m0 = blockIdx.x * 64;                                                \
  const int n0 = blockIdx.y * 64;                                                \
  const int t = threadIdx.x;                                                     \
  {                                                                              \
    const int row = t >> 2, cb = (t & 3) * 64;                                   \
    const u16* ga = A  + (size_t)(m0 + row) * 256 + cb;                          \
    const u16* gb = Bt + (size_t)(n0 + row) * 256 + cb;                          \
    _Pragma("unroll")                                                            \
    for (int i = 0; i < 8; ++i) {                                                \
      *(int4*)&At[row][cb + i * 8] = *(const int4*)(ga + i * 8);                 \
      *(int4*)&Bs[row][cb + i * 8] = *(const int4*)(gb + i * 8);                 \
    }                                                                            \
  }                                                                              \
  __syncthreads();                                                               \
  const int w = t >> 6, l = t & 63, g = l >> 4, c = l & 15;                      \
  f32x4 acc[4] = {};                                                             \
  _Pragma("unroll")                                                              \
  for (int kk = 0; kk < 256; kk += 32) {                                         \
    bf16x8 af = *(const bf16x8*)&At[w * 16 + c][kk + g * 8];                     \
    _Pragma("unroll")                                                            \
    for (int j = 0; j < 4; ++j) {                                                \
      bf16x8 bfr = *(const bf16x8*)&Bs[j * 16 + c][kk + g * 8];                  \
      acc[j] = __builtin_amdgcn_mfma_f32_16x16x32_bf16(af, bfr, acc[j], 0, 0, 0);\
    }                                                                            \
  }

// QKV (q,k part): q scaled by LAMBDA -> [8192][256]; k -> [B][H][2048][32]
__global__ __launch_bounds__(256) void gemm_qk_kernel(
    const u16* __restrict__ A, const u16* __restrict__ Bt, const float* __restrict__ bias,
    u16* __restrict__ qout, u16* __restrict__ kout) {
  GEMM_BODY()
  if (n0 < 256) {
#pragma unroll
    for (int j = 0; j < 4; ++j)
#pragma unroll
      for (int r = 0; r < 4; ++r) {
        int m = m0 + w * 16 + g * 4 + r, n = n0 + j * 16 + c;
        qout[(size_t)m * 256 + n] = bfu((acc[j][r] + bias[n]) * LAMBDA);
      }
  } else {
#pragma unroll
    for (int j = 0; j < 4; ++j)
#pragma unroll
      for (int r = 0; r < 4; ++r) {
        int m = m0 + w * 16 + g * 4 + r, n = n0 + j * 16 + c;
        int ch = n - 256;
        kout[(size_t)((m >> 11) * 8 + (ch >> 5)) * 65536 + (size_t)(m & 2047) * 32 + (ch & 31)]
            = bfu(acc[j][r] + bias[n]);
      }
  }
}

// V^T: A = WvT[256][256], Bt = xb[8192][256] -> vT[256][8192], bias by m(channel)
__global__ __launch_bounds__(256) void gemm_vt_kernel(
    const u16* __restrict__ A, const u16* __restrict__ Bt, const float* __restrict__ bias,
    u16* __restrict__ vtout) {
  GEMM_BODY()
#pragma unroll
  for (int j = 0; j < 4; ++j)
#pragma unroll
    for (int r = 0; r < 4; ++r) {
      int m = m0 + w * 16 + g * 4 + r;   // channel
      int n = n0 + j * 16 + c;           // token
      vtout[(size_t)m * 8192 + n] = bfu(acc[j][r] + bias[m]);
    }
}

// MODE 1: relu + bf16 store. MODE 2: fp32 store of acc+bias+res.
template<int MODE>
__global__ __launch_bounds__(256) void gemm256_kernel(
    const u16* __restrict__ A, const u16* __restrict__ Bt,
    const float* __restrict__ bias, const float* res,
    void* out, int ldout) {
  GEMM_BODY()
#pragma unroll
  for (int j = 0; j < 4; ++j)
#pragma unroll
    for (int r = 0; r < 4; ++r) {
      int m = m0 + w * 16 + g * 4 + r;
      int n = n0 + j * 16 + c;
      float v = acc[j][r] + bias[n];
      size_t oi = (size_t)m * ldout + n;
      if (MODE == 1) {
        ((u16*)out)[oi] = bfu(v > 0.f ? v : 0.f);
      } else {
        ((float*)out)[oi] = v + res[(size_t)m * 256 + n];
      }
    }
}

// ---------------- fused sigmoid-gated attention (swapped-operand, swizzled LDS) -------------
// block = (b, h, 64 q-rows); 4 waves x 16 q. kv tiles of 64, double-buffered, 1 barrier/tile.
__global__ __launch_bounds__(256) void attn_kernel(
    const u16* __restrict__ qb,            // [8192][256] bf16, pre-scaled by LAMBDA
    const u16* __restrict__ kb,            // [B][H][2048][32] bf16
    const u16* __restrict__ vtb,           // [256][8192] bf16 (V^T)
    const unsigned char* __restrict__ m8,  // [2048][2048] 0/1
    u16* __restrict__ ob) {                // [8192][256] bf16
  __shared__ u16 Klds[2][64 * 32];
  __shared__ u16 Vlds[2][32 * 64];
  __shared__ unsigned char Mlds[2][64 * 64];
  __shared__ u32 Plds[4][16][32];

  const int bid = blockIdx.x;
  const int qt = bid & 31, h = (bid >> 5) & 7, b = bid >> 8;
  const int q0 = qt * 64;
  const int t = threadIdx.x, w = t >> 6, l = t & 63, g = (l >> 4), c = l & 15;

  // Q as B-frag (col = q-token = c, k-dim = dh = 8g+j), held in regs
  const bf16x8 qf = *(const bf16x8*)(qb + (size_t)(b * NN + q0 + 16 * w + c) * 256 + h * 32 + 8 * g);
  f32x4 oacc[2] = {};

  // staging addressing
  const int srowK = t >> 2, ssegK = t & 3;       // K & mask tiles: 64 rows x 16B segs
  const int srowV = t >> 3, ssegV = t & 7;       // V^T tile: 32 rows x 16B segs
  const u16* kg = kb + (size_t)(b * 8 + h) * 65536 + (size_t)srowK * 32 + ssegK * 8;
  const u16* vg = vtb + (size_t)(h * 32 + srowV) * 8192 + (size_t)b * NN + ssegV * 8;
  const unsigned char* mg = m8 + (size_t)(q0 + srowK) * NN + ssegK * 16;

  const int kwo = srowK * 32 + ssegK * 8;                 // K LDS write (linear)
  const int vwo = srowV * 64 + ((ssegV ^ (srowV & 7)) * 8); // V^T LDS write (XOR swizzle)
  const int mrowb = srowK * 64;                           // mask rotation by 8*(row&7)
  const int mb0 = (16 * ssegK + 8 * (srowK & 7)) & 63;
  const int mb1 = (mb0 + 8) & 63;

  // prologue: stage tile 0
  uint4 krg = *(const uint4*)kg;
  uint4 vrg = *(const uint4*)vg;
  uint4 mrg = *(const uint4*)mg;
  *(uint4*)&Klds[0][kwo] = krg;
  *(uint4*)&Vlds[0][vwo] = vrg;
  *(uint2*)&Mlds[0][mrowb + mb0] = make_uint2(mrg.x, mrg.y);
  *(uint2*)&Mlds[0][mrowb + mb1] = make_uint2(mrg.z, mrg.w);
  __syncthreads();

  const f32x4 zf = {0.f, 0.f, 0.f, 0.f};
  u32* Pw = &Plds[w][0][0];
  const int pswz = 4 * (c & 7);

  for (int it = 0; it < 32; ++it) {
    const int cur = it & 1;
    if (it < 31) {  // issue next-tile loads early; latency hides under compute
      const int kt = (it + 1) * 64;
      krg = *(const uint4*)(kg + (size_t)kt * 32);
      vrg = *(const uint4*)(vg + kt);
      mrg = *(const uint4*)(mg + kt);
    }
    // S^T = mfma(K, Q): lane(g,c) gets S[q=c][k=16t+4g+r]; gate; pack; wave-private LDS
#pragma unroll
    for (int tt = 0; tt < 4; ++tt) {
      bf16x8 kf = *(const bf16x8*)&Klds[cur][(16 * tt + c) * 32 + 8 * g];
      f32x4 s = __builtin_amdgcn_mfma_f32_16x16x32_bf16(kf, qf, zf, 0, 0, 0);
      u32 mdw = *(const u32*)&Mlds[cur][(16 * w + c) * 64 + ((16 * tt + 4 * g + 8 * (c & 7)) & 63)];
      float mf0 = (float)(mdw & 0xffu);
      float mf1 = (float)((mdw >> 8) & 0xffu);
      float mf2 = (float)((mdw >> 16) & 0xffu);
      float mf3 = (float)(mdw >> 24);
      // masked: s-BIG -> sigmoid == rcp(inf) == 0 exactly
      float s0 = fmaf(mf0, BIGM, s[0] - BIGM);
      float s1 = fmaf(mf1, BIGM, s[1] - BIGM);
      float s2 = fmaf(mf2, BIGM, s[2] - BIGM);
      float s3 = fmaf(mf3, BIGM, s[3] - BIGM);
      float p0 = __builtin_amdgcn_rcpf(1.f + exp2f(-s0));
      float p1 = __builtin_amdgcn_rcpf(1.f + exp2f(-s1));
      float p2 = __builtin_amdgcn_rcpf(1.f + exp2f(-s2));
      float p3 = __builtin_amdgcn_rcpf(1.f + exp2f(-s3));
      u32 w0, w1;
      asm("v_cvt_pk_bf16_f32 %0, %1, %2" : "=v"(w0) : "v"(p0), "v"(p1));
      asm("v_cvt_pk_bf16_f32 %0, %1, %2" : "=v"(w1) : "v"(p2), "v"(p3));
      *(uint2*)&Pw[c * 32 + (((8 * tt + 2 * g) ^ pswz))] = make_uint2(w0, w1);
    }
    // PV: O += P @ V   (P re-read as A-frag from swizzled wave-private LDS)
#pragma unroll
    for (int kk = 0; kk < 2; ++kk) {
      bf16x8 pf = *(const bf16x8*)&Pw[c * 32 + (((16 * kk + 4 * g) ^ pswz))];
#pragma unroll
      for (int d0 = 0; d0 < 2; ++d0) {
        bf16x8 vf = *(const bf16x8*)&Vlds[cur][(16 * d0 + c) * 64 + ((32 * kk + 8 * g) ^ (8 * (c & 7)))];
        oacc[d0] = __builtin_amdgcn_mfma_f32_16x16x32_bf16(pf, vf, oacc[d0], 0, 0, 0);
      }
    }
    if (it < 31) {  // write next tile (other waves finished reading this buffer last iter)
      const int nxt = cur ^ 1;
      *(uint4*)&Klds[nxt][kwo] = krg;
      *(uint4*)&Vlds[nxt][vwo] = vrg;
      *(uint2*)&Mlds[nxt][mrowb + mb0] = make_uint2(mrg.x, mrg.y);
      *(uint2*)&Mlds[nxt][mrowb + mb1] = make_uint2(mrg.z, mrg.w);
    }
    __syncthreads();
  }

  const size_t obase = (size_t)(b * NN + q0 + 16 * w) * 256 + h * 32;
#pragma unroll
  for (int d0 = 0; d0 < 2; ++d0)
#pragma unroll
    for (int r = 0; r < 4; ++r)
      ob[obase + (size_t)(4 * g + r) * 256 + 16 * d0 + c] = bfu(oacc[d0][r]);
}

// ---------------- LayerNorm: wave per row ----------------
template<int WB>
__global__ __launch_bounds__(256) void ln_kernel(const float* y,
    const float* __restrict__ gam, const float* __restrict__ bet,
    float* outf, u16* outb) {
  const int row = blockIdx.x * 4 + (threadIdx.x >> 6);
  const int l = threadIdx.x & 63;
  const float4 v = ((const float4*)(y + (size_t)row * DD))[l];
  float s1 = v.x + v.y + v.z + v.w;
  float s2 = v.x * v.x + v.y * v.y + v.z * v.z + v.w * v.w;
#pragma unroll
  for (int off = 1; off < 64; off <<= 1) {
    s1 += __shfl_xor(s1, off);
    s2 += __shfl_xor(s2, off);
  }
  const float mean = s1 * (1.f / DD);
  const float var = s2 * (1.f / DD) - mean * mean;
  const float inv = rsqrtf(var + 1e-5f);
  const float4 gg = ((const float4*)gam)[l];
  const float4 bb = ((const float4*)bet)[l];
  float o0 = (v.x - mean) * inv * gg.x + bb.x;
  float o1 = (v.y - mean) * inv * gg.y + bb.y;
  float o2 = (v.z - mean) * inv * gg.z + bb.z;
  float o3 = (v.w - mean) * inv * gg.w + bb.w;
  ((float4*)(outf + (size_t)row * DD))[l] = make_float4(o0, o1, o2, o3);
  if (WB) {
    ((ushort4*)(outb + (size_t)row * DD))[l] = make_ushort4(bfu(o0), bfu(o1), bfu(o2), bfu(o3));
  }
}

extern "C" void kernel_launch(void* const* d_in, const int* in_sizes, int n_in,
                              void* d_out, int out_size, void* d_ws, size_t ws_size,
                              hipStream_t stream) {
  const float* qdt   = (const float*)d_in[0];
  const float* boxes = (const float*)d_in[1];
  const int*   mask  = (const int*)d_in[2];
  const float* Wq = (const float*)d_in[3];
  const float* bq = (const float*)d_in[4];
  const float* Wk = (const float*)d_in[5];
  const float* bk = (const float*)d_in[6];
  const float* Wv = (const float*)d_in[7];
  const float* bv = (const float*)d_in[8];
  const float* Wo = (const float*)d_in[9];
  const float* bo = (const float*)d_in[10];
  const float* W1 = (const float*)d_in[11];
  const float* b1 = (const float*)d_in[12];
  const float* W2 = (const float*)d_in[13];
  const float* b2 = (const float*)d_in[14];
  const float* g1  = (const float*)d_in[15];
  const float* be1 = (const float*)d_in[16];
  const float* g2  = (const float*)d_in[17];
  const float* be2 = (const float*)d_in[18];

  char* ws = (char*)d_ws;
  float* x     = (float*)(ws + 0);          // [8192,256] f32 (later reused as y2)
  u16*   xb    = (u16*)  (ws + 8388608);
  u16*   qbuf  = (u16*)  (ws + 12582912);   // q, LAMBDA-scaled
  u16*   kbuf  = (u16*)  (ws + 16777216);   // [B][H][2048][32]
  u16*   vtbuf = (u16*)  (ws + 20971520);   // [256][8192]
  u16*   obuf  = (u16*)  (ws + 25165824);
  float* y1    = (float*)(ws + 29360128);
  u16*   t1b   = (u16*)  (ws + 37748736);
  u16*   f1b   = (u16*)  (ws + 41943040);
  u16*   wqkvT = (u16*)  (ws + 46137344);   // [768,256]
  u16*   woT   = (u16*)  (ws + 46530560);
  u16*   w1T   = (u16*)  (ws + 46661632);
  u16*   w2T   = (u16*)  (ws + 46792704);
  float* bqkv  = (float*)(ws + 46923776);
  unsigned char* m8 = (unsigned char*)(ws + 46926848);

  prep_x_kernel<<<2048, 256, 0, stream>>>(qdt, boxes, x, xb);
  prep_mask_kernel<<<4096, 256, 0, stream>>>(mask, m8);
  prep_w_kernel<<<1539, 256, 0, stream>>>(Wq, Wk, Wv, Wo, W1, W2, bq, bk, bv,
                                          wqkvT, woT, w1T, w2T, bqkv);
  // Q (scaled) + K (relayout): [8192,256] x [256,512]
  gemm_qk_kernel<<<dim3(128, 8), 256, 0, stream>>>(xb, wqkvT, bqkv, qbuf, kbuf);
  // V^T: [256,256] x [256,8192]^T
  gemm_vt_kernel<<<dim3(4, 128), 256, 0, stream>>>(wqkvT + 512 * 256, xb, bqkv + 512, vtbuf);
  // attention
  attn_kernel<<<1024, 256, 0, stream>>>(qbuf, kbuf, vtbuf, m8, obuf);
  // attn_out = O@Wo + bo + x  (fp32)
  gemm256_kernel<2><<<dim3(128, 4), 256, 0, stream>>>(obuf, woT, bo, x, y1, 256);
  // LN1 in-place + bf16 copy
  ln_kernel<1><<<2048, 256, 0, stream>>>(y1, g1, be1, y1, t1b);
  // FF1 + relu
  gemm256_kernel<1><<<dim3(128, 4), 256, 0, stream>>>(t1b, w1T, b1, nullptr, f1b, 256);
  // FF2 + b2 + t1 -> reuse x
  gemm256_kernel<2><<<dim3(128, 4), 256, 0, stream>>>(f1b, w2T, b2, y1, x, 256);
  // LN2 -> d_out
  ln_kernel<0><<<2048, 256, 0, stream>>>(x, g2, be2, (float*)d_out, nullptr);
}